// Round 5
// baseline (716.037 us; speedup 1.0000x reference)
//
#include <hip/hip_runtime.h>

#define T_     24
#define LAMDA_ 0.2f

// output layout (flat f32): outs[24,64,256] | cs[64,256] | las[24,64,32] | gas[24,64,256]
#define OFF_CS  393216
#define OFF_LAS 409600
#define OFF_GAS 458752

__device__ __forceinline__ float clamp15(float x){ return fminf(15.f, fmaxf(-15.f, x)); }
__device__ __forceinline__ float rcp_(float x){ return __builtin_amdgcn_rcpf(x); }

// ---------------------------------------------------------------------------
// R14: R13 regressed (440 vs 420): table build = 48 trans/thread/step > the
// 84 rcp it replaced + 2.5M bank conflicts. Reverted D to R12 pair-rational.
// This round attacks the structure: only 64/256 CUs were active, and Wih
// re-reads (57MB/step chip) put a 1.65us/step L2-BW floor on phase A.
// Now grid=256: 4 sibling blocks per batch, each owns a 64-unit quarter.
//  - A: 192 gate rows/block -> Wih HELD IN REGISTERS (<=18 float4/lane,
//    even slot i+g rows, odd slot o row; gates joined via shfl_down(8));
//    LSTM fused into A tail (phase B + barrier deleted). Zero loads/step.
//  - per-step c-exchange through d_ws: stores -> syncthreads -> tid0
//    release-store stamp (agent scope => L2 wb) -> 192 readers spin-acquire
//    partner stamps + relaxed agent atomic loads (LLC). Double-buffered by
//    t-parity; ws zeroed via hipMemsetAsync each launch (graph-safe).
//  - C (16-lane teams, Wll/Wlg streamed from L2), D (R12 pair-rational),
//    E replicated full per block; outputs flushed as quarters.
//  - co-residency: 256 WGs, 1 WG/CU forced by >80KB LDS pad, 16 waves.
// Tripwires: WRITE>15MB = spill; hang = sync pathology (revert next round).
// ---------------------------------------------------------------------------
__global__ __launch_bounds__(1024, 4) void spat_kernel(
    const float* __restrict__ li,  const float* __restrict__ gi,
    const float* __restrict__ ls,  const float* __restrict__ gs,
    const float* __restrict__ dist,
    const float* __restrict__ la0, const float* __restrict__ ga0,
    const float* __restrict__ Wcl, const float* __restrict__ bcl,
    const float* __restrict__ Wll, const float* __restrict__ bll, const float* __restrict__ vl,
    const float* __restrict__ Wcg, const float* __restrict__ bcg,
    const float* __restrict__ Wlg, const float* __restrict__ blg, const float* __restrict__ vg,
    const float* __restrict__ Wih, const float* __restrict__ bih, const float* __restrict__ bhh,
    float* __restrict__ ws, float* __restrict__ out)
{
    __shared__ float Eg[6144];               // exp(2*hf_g[o][s]), o<24, s<256 (full, replicated)
    __shared__ float El[800];                // exp(2*hf_l), idx l*25+o (full)
    __shared__ float outb[1536];             // h quarter   [t][64]
    __shared__ float gasb[1536];             // gas quarter [t][64]
    __shared__ float lasb[192];              // las quarter [t][8]
    __shared__ float csb[64];                // c quarter at t=23
    __shared__ __align__(16) union {
        float wcg[6144];                     // Wcg staging (init only)
        struct {
            float sgred[1024];
            float cqf[256];                  // FULL c vector (own quarter + exchanged)
            float xv[288];
            float slg[32];
        } p;
    } U;
    __shared__ float dstf[256];
    __shared__ float bcf[48];                // bll|blg
    __shared__ __align__(16) float4 pl4[12], pg4[12];  // pair coeffs (A0,A1,B1,B2)
    __shared__ float vlf[24], vgf[24], cbuf[2];
    // occupancy-shaping pad: LDS > 80KB -> 1 WG/CU (hard co-residency for the
    // 256-block grid) and keeps the 128-VGPR budget recipe from R11/R12.
    __shared__ float ldspad[5632];

    const int bid = blockIdx.x;
    const int b = bid >> 2, K = bid & 3;     // batch, sibling index
    const int tid = threadIdx.x;
    const int s = tid & 255, ogrp = tid >> 8;

    float* wsb = ws + (size_t)b * 1024;      // per-batch ws: c-data[2][4][64] | stamps
    int*   wst = (int*)(wsb + 512);          // stamps [2 parity][4 K]

    // keep-alive for ldspad (branch never taken)
    if (__builtin_expect((int)blockIdx.x == 0x7fffffff, 0)) {
        ldspad[tid] = bcg[0];
        out[0] = ldspad[tid ^ 1];
    }

    // ---- small init (before first barrier) ----
    if (tid < 256) dstf[tid] = dist[b*256 + tid];
    if (tid < 24)  { vlf[tid] = vl[tid]; vgf[tid] = vg[tid]; }
    if (tid < 48)  bcf[tid] = (tid < 24) ? bll[tid] : blg[tid - 24];
    if (tid == 0)  { float s1 = 0.f; for (int d = 0; d < 24; d++) s1 += vl[d]; cbuf[0] = s1; }
    if (tid == 1)  { float s1 = 0.f; for (int d = 0; d < 24; d++) s1 += vg[d]; cbuf[1] = s1; }

    // ---- per-thread unit assignment + biases + Wih register preload ----
    const int slot = tid >> 3, u8 = tid & 7;
    const int pairu = slot >> 1;             // 0..63 local unit
    const bool isEven = (slot & 1) == 0;
    const int u_glob = K*64 + pairu;         // unit index within batch
    const float bsI = bih[u_glob]     + bhh[u_glob];
    const float bsG = bih[512+u_glob] + bhh[512+u_glob];
    const float bsO = bih[768+u_glob] + bhh[768+u_glob];

    float4 wA[9], wB[9];                     // even: i-row, g-row; odd: o-row
    {
        const float4* W4 = (const float4*)Wih;
        const int cb = u8*9;
        if (isEven) {
#pragma unroll
            for (int m = 0; m < 9; m++) {
                wA[m] = W4[(size_t)u_glob*72 + cb + m];
                wB[m] = W4[(size_t)(512+u_glob)*72 + cb + m];
            }
        } else {
#pragma unroll
            for (int m = 0; m < 9; m++) {
                wA[m] = W4[(size_t)(768+u_glob)*72 + cb + m];
                wB[m] = make_float4(0.f,0.f,0.f,0.f);
            }
        }
    }

    // ---- hf_g (FULL, replicated): thread (s, ogrp) accumulates 6 o's ----
    float acc[6];
#pragma unroll
    for (int i = 0; i < 6; i++) acc[i] = bcg[ogrp*6 + i];

    for (int hc = 0; hc < 3; hc++) {
        for (int k = tid; k < 6144; k += 1024) {
            const int o = k >> 8, r = k & 255;
            U.wcg[k] = Wcg[o*768 + hc*256 + r];
        }
        __syncthreads();
        for (int cc = 0; cc < 8; cc++) {
            const int c = hc*8 + cc;
            const float4* gp = (const float4*)(gs + ((size_t)b*196608 + c*8192 + s*32));
#pragma unroll
            for (int h = 0; h < 2; h++) {
                float gv[16];
#pragma unroll
                for (int m = 0; m < 4; m++) {
                    const float4 g = gp[h*4 + m];
                    gv[4*m] = g.x; gv[4*m+1] = g.y; gv[4*m+2] = g.z; gv[4*m+3] = g.w;
                }
#pragma unroll
                for (int i = 0; i < 6; i++) {
                    const float4* wp = (const float4*)(U.wcg + ((ogrp*6 + i)*256 + cc*32)) + h*4;
                    float a = acc[i];
#pragma unroll
                    for (int m = 0; m < 4; m++) {
                        const float4 w = wp[m];
                        a = fmaf(w.x, gv[4*m],   a);
                        a = fmaf(w.y, gv[4*m+1], a);
                        a = fmaf(w.z, gv[4*m+2], a);
                        a = fmaf(w.w, gv[4*m+3], a);
                    }
                    acc[i] = a;
                }
            }
        }
        __syncthreads();
    }
#pragma unroll
    for (int i = 0; i < 6; i++) Eg[(ogrp*6 + i)*256 + s] = __expf(2.f*clamp15(acc[i]));

    // ---- hf_l -> El (FULL, replicated; idx l*25+o) ----
    if (tid < 768) {
        const int o = tid >> 5, l = tid & 31;
        float a = bcl[o];
        for (int c = 0; c < 24; c++)
            a = fmaf(Wcl[o*24 + c], ls[b*768 + c*32 + l], a);
        El[l*25 + o] = __expf(2.f*clamp15(a));
    }

    // ---- x for t=0 ----
    if (tid < 288) {
        if (tid < 32) U.p.xv[tid] = la0[b*32 + tid] * li[b*32 + tid];
        else { const int ss = tid - 32; U.p.xv[tid] = ga0[b*256 + ss] * gi[b*256 + ss]; }
    }
    __syncthreads();

    const int lg = tid >> 5, ol = tid & 31;    // phase-D s_l layout

    for (int t = 0; t < T_; t++) {
        // prefetch next-step inputs for the fused x-build (wave0: li, wave1: gi)
        float liN = 0.f;
        float giN0 = 0.f, giN1 = 0.f, giN2 = 0.f, giN3 = 0.f;
        if (t < T_ - 1) {
            if (tid < 32) liN = li[(t+1)*2048 + b*32 + tid];
            else if (tid >= 64 && tid < 128) {
                const int lane = tid - 64;
                giN0 = gi[(t+1)*16384 + b*256 + lane];
                giN1 = gi[(t+1)*16384 + b*256 + lane + 64];
                giN2 = gi[(t+1)*16384 + b*256 + lane + 128];
                giN3 = gi[(t+1)*16384 + b*256 + lane + 192];
            }
        }

        // ---- A: register-resident GEMV (own 192 rows) + fused LSTM ----
        {
            const float4* xp4 = (const float4*)U.p.xv;
            float aA = 0.f, aB = 0.f;
#pragma unroll
            for (int m = 0; m < 9; m++) {
                const float4 x4 = xp4[u8*9 + m];
                aA = fmaf(wA[m].x, x4.x, aA); aA = fmaf(wA[m].y, x4.y, aA);
                aA = fmaf(wA[m].z, x4.z, aA); aA = fmaf(wA[m].w, x4.w, aA);
                if (isEven) {
                    aB = fmaf(wB[m].x, x4.x, aB); aB = fmaf(wB[m].y, x4.y, aB);
                    aB = fmaf(wB[m].z, x4.z, aB); aB = fmaf(wB[m].w, x4.w, aB);
                }
            }
            aA += __shfl_xor(aA, 1); aA += __shfl_xor(aA, 2); aA += __shfl_xor(aA, 4);
            aB += __shfl_xor(aB, 1); aB += __shfl_xor(aB, 2); aB += __shfl_xor(aB, 4);
            const float aO = __shfl_down(aA, 8);   // odd slot's o-row sum (all lanes exec)
            if ((tid & 15) == 0) {
                const float ig = aA + bsI, gg = aB + bsG, ot = aO + bsO;
                const float sig_i = rcp_(1.f + __expf(-ig));
                const float th_g  = 1.f - 2.f*rcp_(1.f + __expf(2.f*clamp15(gg)));
                const float c     = sig_i * th_g;
                const float sig_o = rcp_(1.f + __expf(-ot));
                const float th_c  = 1.f - 2.f*rcp_(1.f + __expf(2.f*c));
                const float h     = sig_o * th_c;
                U.p.cqf[u_glob] = c;
                outb[t*64 + pairu] = h;
                if (t == T_ - 1) csb[pairu] = c;
                wsb[(t&1)*256 + K*64 + pairu] = c;   // publish own quarter
            }
        }
        __syncthreads();                              // #1: own writes done

        // ---- exchange: release own stamp, pull 3 partner quarters ----
        if (tid == 0)
            __hip_atomic_store(&wst[(t&1)*4 + K], t+1,
                               __ATOMIC_RELEASE, __HIP_MEMORY_SCOPE_AGENT);
        if (tid < 192) {
            const int pp = tid >> 6;
            const int P  = pp + (pp >= K ? 1 : 0);
            const int j  = tid & 63;
            while (__hip_atomic_load(&wst[(t&1)*4 + P],
                                     __ATOMIC_ACQUIRE, __HIP_MEMORY_SCOPE_AGENT) != t+1)
                __builtin_amdgcn_s_sleep(1);
            U.p.cqf[P*64 + j] =
                __hip_atomic_load(&wsb[(t&1)*256 + P*64 + j],
                                  __ATOMIC_RELAXED, __HIP_MEMORY_SCOPE_AGENT);
        }
        __syncthreads();                              // #2: cqf full

        // ---- C: 48 dots x 16-lane teams over full cqf; pair coeffs ----
        if (tid < 768) {
            const int dot = tid >> 4, l16 = tid & 15;
            const float* Wr = (dot < 24) ? (Wll + dot*256) : (Wlg + (dot - 24)*256);
            const float4* wp = (const float4*)Wr + l16*4;
            const float4* cp = (const float4*)U.p.cqf + l16*4;
            float a0 = 0.f, a1 = 0.f;
#pragma unroll
            for (int m = 0; m < 4; m += 2) {
                const float4 w0 = wp[m],   c0 = cp[m];
                const float4 w1 = wp[m+1], c1 = cp[m+1];
                a0 = fmaf(w0.x,c0.x,a0); a0 = fmaf(w0.y,c0.y,a0);
                a0 = fmaf(w0.z,c0.z,a0); a0 = fmaf(w0.w,c0.w,a0);
                a1 = fmaf(w1.x,c1.x,a1); a1 = fmaf(w1.y,c1.y,a1);
                a1 = fmaf(w1.z,c1.z,a1); a1 = fmaf(w1.w,c1.w,a1);
            }
            float a = a0 + a1;
            a += __shfl_xor(a, 1); a += __shfl_xor(a, 2);
            a += __shfl_xor(a, 4); a += __shfl_xor(a, 8);
            const float F  = __expf(2.f*clamp15(a + bcf[dot]));
            const float v  = (dot < 24) ? vlf[dot] : vgf[dot - 24];
            const float Fo = __shfl_xor(F, 16);        // partner team (dot^1)
            const float vo = (dot < 24) ? vlf[dot ^ 1] : vgf[(dot ^ 1) - 24];
            if ((tid & 31) == 0) {                     // lane 0 of even dot
                const float A0 = v + vo;
                const float A1 = fmaf(v, Fo, vo * F);
                const float B1 = F + Fo;
                const float B2 = F * Fo;
                const int P2 = dot >> 1;               // 0..23
                if (P2 < 12) pl4[P2]      = make_float4(A0, A1, B1, B2);
                else         pg4[P2 - 12] = make_float4(A0, A1, B1, B2);
            }
        }
        __syncthreads();                              // #3

        // ---- D: s_g partials (all, 6 o x 12 pairs) + s_l (shfl-reduce) ----
        {
            float z[6], z2[6];
#pragma unroll
            for (int i = 0; i < 6; i++) {
                z[i]  = Eg[(ogrp*6 + i)*256 + s];
                z2[i] = z[i]*z[i];
            }
            float a0 = 0.f;
#pragma unroll 4
            for (int p = 0; p < 12; p++) {
                const float4 q = pg4[p];
#pragma unroll
                for (int i = 0; i < 6; i++) {
                    const float num = fmaf(z[i],  q.y, q.x);
                    const float den = fmaf(z2[i], q.w, fmaf(z[i], q.z, 1.f));
                    a0 = fmaf(num, rcp_(den), a0);
                }
            }
            U.p.sgred[tid] = a0;
        }
        {
            float bsl = 0.f;
            if (ol < 24) {
                const float E  = El[lg*25 + ol];
                const float E2 = E*E;
#pragma unroll 4
                for (int p = 0; p < 12; p++) {
                    const float4 q = pl4[p];
                    const float num = fmaf(E,  q.y, q.x);
                    const float den = fmaf(E2, q.w, fmaf(E, q.z, 1.f));
                    bsl = fmaf(num, rcp_(den), bsl);
                }
            }
            bsl += __shfl_xor(bsl, 1);  bsl += __shfl_xor(bsl, 2);
            bsl += __shfl_xor(bsl, 4);  bsl += __shfl_xor(bsl, 8);
            bsl += __shfl_xor(bsl, 16);
            if (ol == 0) U.p.slg[lg] = bsl;
        }
        __syncthreads();                              // #4

        // ---- E: both softmaxes (replicated) + quarter writes + x-build ----
        if (tid < 32) {                       // wave0: s_l softmax
            const float sv = 24.f*cbuf[0] - 2.f*U.p.slg[tid];
            float m = sv;
#pragma unroll
            for (int mk = 16; mk >= 1; mk >>= 1) m = fmaxf(m, __shfl_xor(m, mk));
            const float e = __expf(sv - m);
            float ss = e;
#pragma unroll
            for (int mk = 16; mk >= 1; mk >>= 1) ss += __shfl_xor(ss, mk);
            const float r = e * rcp_(ss);
            if ((tid >> 3) == K) lasb[t*8 + (tid & 7)] = r;
            if (t < T_ - 1) U.p.xv[tid] = r * liN;
        } else if (tid >= 64 && tid < 128) {  // wave1: s_g softmax, 4 s/lane
            const int lane = tid - 64;
            float vv0, vv1, vv2, vv3;
            {
                const float t0 = U.p.sgred[lane]     + U.p.sgred[256+lane]     + U.p.sgred[512+lane]     + U.p.sgred[768+lane];
                const float t1 = U.p.sgred[lane+64]  + U.p.sgred[256+lane+64]  + U.p.sgred[512+lane+64]  + U.p.sgred[768+lane+64];
                const float t2 = U.p.sgred[lane+128] + U.p.sgred[256+lane+128] + U.p.sgred[512+lane+128] + U.p.sgred[768+lane+128];
                const float t3 = U.p.sgred[lane+192] + U.p.sgred[256+lane+192] + U.p.sgred[512+lane+192] + U.p.sgred[768+lane+192];
                vv0 = (1.f-LAMDA_)*(24.f*cbuf[1] - 2.f*t0) + LAMDA_*dstf[lane];
                vv1 = (1.f-LAMDA_)*(24.f*cbuf[1] - 2.f*t1) + LAMDA_*dstf[lane+64];
                vv2 = (1.f-LAMDA_)*(24.f*cbuf[1] - 2.f*t2) + LAMDA_*dstf[lane+128];
                vv3 = (1.f-LAMDA_)*(24.f*cbuf[1] - 2.f*t3) + LAMDA_*dstf[lane+192];
            }
            float m = fmaxf(fmaxf(vv0, vv1), fmaxf(vv2, vv3));
#pragma unroll
            for (int mk = 32; mk >= 1; mk >>= 1) m = fmaxf(m, __shfl_xor(m, mk));
            const float e0 = __expf(vv0 - m), e1 = __expf(vv1 - m);
            const float e2 = __expf(vv2 - m), e3 = __expf(vv3 - m);
            float ss = (e0 + e1) + (e2 + e3);
#pragma unroll
            for (int mk = 32; mk >= 1; mk >>= 1) ss += __shfl_xor(ss, mk);
            const float inv = rcp_(ss);
            const float r0 = e0*inv, r1 = e1*inv, r2 = e2*inv, r3 = e3*inv;
            const float rK = (K == 0) ? r0 : (K == 1) ? r1 : (K == 2) ? r2 : r3;
            gasb[t*64 + lane] = rK;                   // own s-quarter (s = 64K+lane)
            if (t < T_ - 1) {
                U.p.xv[32+lane]     = r0 * giN0;
                U.p.xv[32+lane+64]  = r1 * giN1;
                U.p.xv[32+lane+128] = r2 * giN2;
                U.p.xv[32+lane+192] = r3 * giN3;
            }
        }
        __syncthreads();                              // #5
    }

    // ---- final flush: quarter buffers -> global ----
    for (int k = tid; k < 1536; k += 1024) {
        const int tt = k >> 6, j = k & 63;
        out[tt*16384 + b*256 + K*64 + j]           = outb[k];
        out[OFF_GAS + tt*16384 + b*256 + K*64 + j] = gasb[k];
    }
    if (tid < 192) {
        const int tt = tid >> 3, j = tid & 7;
        out[OFF_LAS + tt*2048 + b*32 + K*8 + j] = lasb[tid];
    }
    if (tid < 64) out[OFF_CS + b*256 + K*64 + tid] = csb[tid];
}

extern "C" void kernel_launch(void* const* d_in, const int* in_sizes, int n_in,
                              void* d_out, int out_size, void* d_ws, size_t ws_size,
                              hipStream_t stream)
{
    const float* li   = (const float*)d_in[0];
    const float* gi   = (const float*)d_in[1];
    const float* ls   = (const float*)d_in[2];
    const float* gs   = (const float*)d_in[3];
    const float* dist = (const float*)d_in[4];
    const float* la0  = (const float*)d_in[5];
    const float* ga0  = (const float*)d_in[6];
    const float* Wcl  = (const float*)d_in[7];
    const float* bcl  = (const float*)d_in[8];
    const float* Wll  = (const float*)d_in[9];
    const float* bll  = (const float*)d_in[10];
    const float* vl   = (const float*)d_in[11];
    const float* Wcg  = (const float*)d_in[12];
    const float* bcg  = (const float*)d_in[13];
    const float* Wlg  = (const float*)d_in[14];
    const float* blg  = (const float*)d_in[15];
    const float* vg   = (const float*)d_in[16];
    const float* Wih  = (const float*)d_in[17];
    const float* bih  = (const float*)d_in[18];
    const float* bhh  = (const float*)d_in[19];

    // zero the exchange workspace (stamps must not be garbage on first use).
    // 64 batches x 1024 floats = 256KB. MemsetAsync is graph-capture-safe.
    hipMemsetAsync(d_ws, 0, 64 * 1024 * sizeof(float), stream);

    spat_kernel<<<256, 1024, 0, stream>>>(li, gi, ls, gs, dist, la0, ga0,
                                          Wcl, bcl, Wll, bll, vl,
                                          Wcg, bcg, Wlg, blg, vg,
                                          Wih, bih, bhh,
                                          (float*)d_ws, (float*)d_out);
}